// Round 2
// baseline (2397.321 us; speedup 1.0000x reference)
//
#include <hip/hip_runtime.h>

#define D_    784
#define ROWS  8            // rows (batch elems) per block
#define STR   9            // LDS row stride: 9 coprime with 32 -> conflict-free writes/FC
#define NCLS  10
#define BLOCK 256
#define NGRP  (BLOCK / ROWS)   // 32 groups of 8 lanes; group owns n = g + 32*i
#define NPG   25               // ceil(784/32) n's per group
#define NB    (65536 / ROWS)   // 8192 blocks

// gelu = x * e/(e+1), e = exp(2*0.79788456*(x + 0.044715 x^3))  [tanh-GELU, |err|~3e-4]
__device__ __forceinline__ float gelu_f(float x) {
    float x2    = x * x;
    float inner = fmaf(0.044715f * x, x2, x);
    float e     = exp2f(2.3022082f * inner);              // 2*0.79788456*log2(e)
    float r     = __builtin_amdgcn_rcpf(e + 1.0f);
    return fmaf(-x, r, x);                                // x - x/(e+1) = x*e/(e+1)
}

// In-place sparse layer: read-all (regs) -> barrier -> write-all -> barrier.
// Thread (g, r): accumulates outputs for n = g + 32*i, row r.
// Gather read h[j*STR + r]: 8 lanes of a group hit 8 consecutive banks.
template <int K>
__device__ __forceinline__ void layer_fn(float* __restrict__ h,
                                         const int* __restrict__ idx,
                                         const float* __restrict__ w,
                                         const float* __restrict__ bias,
                                         int g, int r) {
    float acc[NPG];
#pragma unroll
    for (int i = 0; i < NPG; ++i) {
        int n = g + NGRP * i;
        float a = 0.0f;
        if (n < D_) {
            a = bias[n];
#pragma unroll
            for (int k = 0; k < K; ++k) {
                int   j  = idx[n * K + k];
                float wk = w[n * K + k];
                a = fmaf(h[j * STR + r], wk, a);
            }
        }
        acc[i] = a;
    }
    __syncthreads();
#pragma unroll
    for (int i = 0; i < NPG; ++i) {
        int n = g + NGRP * i;
        if (n < D_) h[n * STR + r] = gelu_f(acc[i]);
    }
    __syncthreads();
}

__global__ __launch_bounds__(BLOCK, 5)
void circnn_kernel(const float* __restrict__ x,
                   const int* __restrict__ idx1, const float* __restrict__ w1, const float* __restrict__ b1,
                   const int* __restrict__ idx2, const float* __restrict__ w2, const float* __restrict__ b2,
                   const int* __restrict__ idx3, const float* __restrict__ w3, const float* __restrict__ b3,
                   const float* __restrict__ fcw, const float* __restrict__ fcb,
                   float* __restrict__ out) {
    __shared__ __align__(16) float h[D_ * STR];          // 28224 B, layout h[n*9 + r]
    __shared__ float red[NGRP * NCLS];                   // per-(wave,row) FC partials
    __shared__ float logits[ROWS * NCLS];

    const int tid  = threadIdx.x;
    const int g    = tid >> 3;        // group 0..31
    const int r    = tid & 7;         // row 0..7
    const int row0 = blockIdx.x * ROWS;

    // ---- Stage x: coalesced global b32 reads; LDS writes stride 9 (conflict-free)
    const float* xb = x + (size_t)row0 * D_;
    for (int v = tid; v < ROWS * D_; v += BLOCK) {
        int rr = v / D_;
        int nn = v - rr * D_;
        h[nn * STR + rr] = xb[v];
    }
    __syncthreads();

    // ---- Three sparse layers, in place
    layer_fn<2>(h, idx1, w1, b1, g, r);
    layer_fn<4>(h, idx2, w2, b2, g, r);
    layer_fn<8>(h, idx3, w3, b3, g, r);

    // ---- FC 784 -> 10. Thread (r2 = tid&7, jj = tid>>3): n = jj + 32*i
    const int r2 = tid & 7;
    const int jj = tid >> 3;
    float facc[NCLS];
#pragma unroll
    for (int c = 0; c < NCLS; ++c) facc[c] = 0.0f;
    for (int n = jj; n < D_; n += NGRP) {
        float hv = h[n * STR + r2];
#pragma unroll
        for (int c = 0; c < NCLS; ++c)
            facc[c] = fmaf(hv, fcw[c * D_ + n], facc[c]);
    }
    // reduce over jj-within-wave (tid bits 3..5)
#pragma unroll
    for (int m = 8; m <= 32; m <<= 1) {
#pragma unroll
        for (int c = 0; c < NCLS; ++c)
            facc[c] += __shfl_xor(facc[c], m, 64);
    }
    const int lane = tid & 63;
    const int wv   = tid >> 6;
    if (lane < 8) {
#pragma unroll
        for (int c = 0; c < NCLS; ++c)
            red[(wv * 8 + lane) * NCLS + c] = facc[c];
    }
    __syncthreads();

    // combine 4 wave partials -> logits[r][c]
    if (tid < ROWS * NCLS) {
        int rr = tid / NCLS, c = tid - rr * NCLS;
        float s = fcb[c];
#pragma unroll
        for (int w4 = 0; w4 < 4; ++w4)
            s += red[(w4 * 8 + rr) * NCLS + c];
        logits[rr * NCLS + c] = s;
    }
    __syncthreads();

    // ---- softmax per row, write 10 floats
    if (tid < ROWS) {
        int rr = tid;
        float m = logits[rr * NCLS];
#pragma unroll
        for (int c = 1; c < NCLS; ++c) m = fmaxf(m, logits[rr * NCLS + c]);
        float e[NCLS];
        float s = 0.f;
#pragma unroll
        for (int c = 0; c < NCLS; ++c) {
            e[c] = __expf(logits[rr * NCLS + c] - m);
            s += e[c];
        }
        float inv = 1.0f / s;
        float* op = out + (size_t)(row0 + rr) * NCLS;
#pragma unroll
        for (int c = 0; c < NCLS; ++c) op[c] = e[c] * inv;
    }
}

extern "C" void kernel_launch(void* const* d_in, const int* in_sizes, int n_in,
                              void* d_out, int out_size, void* d_ws, size_t ws_size,
                              hipStream_t stream) {
    const float* x    = (const float*)d_in[0];
    const int*   idx1 = (const int*)d_in[1];
    const float* w1   = (const float*)d_in[2];
    const float* b1   = (const float*)d_in[3];
    const int*   idx2 = (const int*)d_in[4];
    const float* w2   = (const float*)d_in[5];
    const float* b2   = (const float*)d_in[6];
    const int*   idx3 = (const int*)d_in[7];
    const float* w3   = (const float*)d_in[8];
    const float* b3   = (const float*)d_in[9];
    const float* fcw  = (const float*)d_in[10];
    const float* fcb  = (const float*)d_in[11];
    float* out = (float*)d_out;

    circnn_kernel<<<dim3(NB), dim3(BLOCK), 0, stream>>>(
        x, idx1, w1, b1, idx2, w2, b2, idx3, w3, b3, fcw, fcb, out);
}

// Round 3
// 1420.580 us; speedup vs baseline: 1.6876x; 1.6876x over previous
//
#include <hip/hip_runtime.h>

#define D_    784
#define ROWS  32              // batch rows per block
#define NCLS  10
#define BLOCK 1024            // 16 waves
#define NWAVE 16
#define NPG   13              // n's per 16-lane group: n = g2 + 64*i (guard last)
#define NB    (65536 / ROWS)  // 2048 blocks
#define HSTR  34              // dword stride per n (even -> b64-aligned row pairs)

// ---- swizzled LDS layout -------------------------------------------------
// logical (n, row r): row-pair p = r>>1 is stored at pair-slot (p + (n>>2)) & 15.
// dword offset; all 16 pair-slots are bank-disjoint across a 16-lane group.
__device__ __forceinline__ int hoff_pair(int n, int p) {
    int s = (p + (n >> 2)) & 15;
    return n * HSTR + (s << 1);
}
__device__ __forceinline__ int hoff(int n, int r) {
    return hoff_pair(n, r >> 1) + (r & 1);
}

// tanh-approx GELU (|err| vs exact ~5e-4)
__device__ __forceinline__ float gelu_f(float x) {
    float x2    = x * x;
    float inner = fmaf(0.044715f * x, x2, x);
    float e     = exp2f(2.3022082f * inner);             // 2*0.79788456/ln2... *log2e
    float r     = __builtin_amdgcn_rcpf(e + 1.0f);
    return fmaf(-x, r, x);                               // x*e/(e+1)
}

// In-place sparse layer. Thread (g2 = tid>>4, p = tid&15) owns row-pair p for
// n = g2 + 64*i. Gathers are b64 (float2 of rows 2p,2p+1), conflict-free.
template <int K>
__device__ __forceinline__ void layer_fn(float* __restrict__ h,
                                         const int* __restrict__ idx,
                                         const float* __restrict__ w,
                                         const float* __restrict__ bias,
                                         int g2, int p) {
    float2 acc[NPG];
#pragma unroll
    for (int i = 0; i < NPG; ++i) {
        int n = g2 + 64 * i;
        float2 a = make_float2(0.f, 0.f);
        if (n < D_) {
            float bv = bias[n];
            a.x = bv; a.y = bv;
            if constexpr (K == 2) {
                int2   j2 = *(const int2*)(idx + n * 2);
                float2 w2 = *(const float2*)(w + n * 2);
                float2 h0 = *(const float2*)(h + hoff_pair(j2.x, p));
                float2 h1 = *(const float2*)(h + hoff_pair(j2.y, p));
                a.x = fmaf(h0.x, w2.x, a.x); a.y = fmaf(h0.y, w2.x, a.y);
                a.x = fmaf(h1.x, w2.y, a.x); a.y = fmaf(h1.y, w2.y, a.y);
            } else if constexpr (K == 4) {
                int4   j4 = *(const int4*)(idx + n * 4);
                float4 w4 = *(const float4*)(w + n * 4);
                float2 h0 = *(const float2*)(h + hoff_pair(j4.x, p));
                float2 h1 = *(const float2*)(h + hoff_pair(j4.y, p));
                float2 h2 = *(const float2*)(h + hoff_pair(j4.z, p));
                float2 h3 = *(const float2*)(h + hoff_pair(j4.w, p));
                a.x = fmaf(h0.x, w4.x, a.x); a.y = fmaf(h0.y, w4.x, a.y);
                a.x = fmaf(h1.x, w4.y, a.x); a.y = fmaf(h1.y, w4.y, a.y);
                a.x = fmaf(h2.x, w4.z, a.x); a.y = fmaf(h2.y, w4.z, a.y);
                a.x = fmaf(h3.x, w4.w, a.x); a.y = fmaf(h3.y, w4.w, a.y);
            } else { // K == 8
                int4   ja = *(const int4*)(idx + n * 8);
                int4   jb = *(const int4*)(idx + n * 8 + 4);
                float4 wa = *(const float4*)(w + n * 8);
                float4 wb = *(const float4*)(w + n * 8 + 4);
                float2 h0 = *(const float2*)(h + hoff_pair(ja.x, p));
                float2 h1 = *(const float2*)(h + hoff_pair(ja.y, p));
                float2 h2 = *(const float2*)(h + hoff_pair(ja.z, p));
                float2 h3 = *(const float2*)(h + hoff_pair(ja.w, p));
                a.x = fmaf(h0.x, wa.x, a.x); a.y = fmaf(h0.y, wa.x, a.y);
                a.x = fmaf(h1.x, wa.y, a.x); a.y = fmaf(h1.y, wa.y, a.y);
                a.x = fmaf(h2.x, wa.z, a.x); a.y = fmaf(h2.y, wa.z, a.y);
                a.x = fmaf(h3.x, wa.w, a.x); a.y = fmaf(h3.y, wa.w, a.y);
                float2 h4 = *(const float2*)(h + hoff_pair(jb.x, p));
                float2 h5 = *(const float2*)(h + hoff_pair(jb.y, p));
                float2 h6 = *(const float2*)(h + hoff_pair(jb.z, p));
                float2 h7 = *(const float2*)(h + hoff_pair(jb.w, p));
                a.x = fmaf(h4.x, wb.x, a.x); a.y = fmaf(h4.y, wb.x, a.y);
                a.x = fmaf(h5.x, wb.y, a.x); a.y = fmaf(h5.y, wb.y, a.y);
                a.x = fmaf(h6.x, wb.z, a.x); a.y = fmaf(h6.y, wb.z, a.y);
                a.x = fmaf(h7.x, wb.w, a.x); a.y = fmaf(h7.y, wb.w, a.y);
            }
        }
        acc[i] = a;
    }
    __syncthreads();
#pragma unroll
    for (int i = 0; i < NPG; ++i) {
        int n = g2 + 64 * i;
        if (n < D_) {
            float2 gv = make_float2(gelu_f(acc[i].x), gelu_f(acc[i].y));
            *(float2*)(h + hoff_pair(n, p)) = gv;
        }
    }
    __syncthreads();
}

__global__ __launch_bounds__(BLOCK, 4)
void circnn_kernel(const float* __restrict__ x,
                   const int* __restrict__ idx1, const float* __restrict__ w1, const float* __restrict__ b1,
                   const int* __restrict__ idx2, const float* __restrict__ w2, const float* __restrict__ b2,
                   const int* __restrict__ idx3, const float* __restrict__ w3, const float* __restrict__ b3,
                   const float* __restrict__ fcw, const float* __restrict__ fcb,
                   float* __restrict__ out) {
    __shared__ __align__(16) float  h[D_ * HSTR];        // 106,624 B
    __shared__ __align__(16) float2 red2[NWAVE * 16 * NCLS]; // 20,480 B
    __shared__ float logits[ROWS * NCLS];                // 1,280 B

    const int tid  = threadIdx.x;
    const int g2   = tid >> 4;        // 0..63 group id
    const int p    = tid & 15;        // row-pair 0..15
    const int row0 = blockIdx.x * ROWS;

    // ---- Stage x (float4 global, swizzled scalar LDS writes) ----
    const float4* xv = (const float4*)(x + (size_t)row0 * D_);
    for (int q = tid; q < (ROWS * D_) / 4; q += BLOCK) {   // 6272 quads
        float4 v = xv[q];
        int r = q / (D_ / 4);                              // /196
        int n = (q - r * (D_ / 4)) * 4;
        h[hoff(n,     r)] = v.x;
        h[hoff(n + 1, r)] = v.y;
        h[hoff(n + 2, r)] = v.z;
        h[hoff(n + 3, r)] = v.w;
    }
    __syncthreads();

    // ---- Three sparse layers, in place ----
    layer_fn<2>(h, idx1, w1, b1, g2, p);
    layer_fn<4>(h, idx2, w2, b2, g2, p);
    layer_fn<8>(h, idx3, w3, b3, g2, p);

    // ---- FC 784->10: thread (p2 = tid&15 row-pair, jj = tid>>4) ----
    const int p2 = tid & 15;
    const int jj = tid >> 4;          // 0..63
    float2 facc[NCLS];
#pragma unroll
    for (int c = 0; c < NCLS; ++c) facc[c] = make_float2(0.f, 0.f);
    for (int i = 0; i < 4; ++i) {
        int q = jj + 64 * i;
        if (q < D_ / 4) {             // 196 quads
            int n = q * 4;
            float2 h0 = *(const float2*)(h + hoff_pair(n,     p2));
            float2 h1 = *(const float2*)(h + hoff_pair(n + 1, p2));
            float2 h2 = *(const float2*)(h + hoff_pair(n + 2, p2));
            float2 h3 = *(const float2*)(h + hoff_pair(n + 3, p2));
#pragma unroll
            for (int c = 0; c < NCLS; ++c) {
                float4 wv = *(const float4*)(fcw + c * D_ + n);
                facc[c].x = fmaf(h0.x, wv.x, facc[c].x);
                facc[c].y = fmaf(h0.y, wv.x, facc[c].y);
                facc[c].x = fmaf(h1.x, wv.y, facc[c].x);
                facc[c].y = fmaf(h1.y, wv.y, facc[c].y);
                facc[c].x = fmaf(h2.x, wv.z, facc[c].x);
                facc[c].y = fmaf(h2.y, wv.z, facc[c].y);
                facc[c].x = fmaf(h3.x, wv.w, facc[c].x);
                facc[c].y = fmaf(h3.y, wv.w, facc[c].y);
            }
        }
    }
    // reduce over jj bits inside the wave (tid bits 4,5)
#pragma unroll
    for (int c = 0; c < NCLS; ++c) {
        facc[c].x += __shfl_xor(facc[c].x, 16, 64);
        facc[c].y += __shfl_xor(facc[c].y, 16, 64);
        facc[c].x += __shfl_xor(facc[c].x, 32, 64);
        facc[c].y += __shfl_xor(facc[c].y, 32, 64);
    }
    const int wv_  = tid >> 6;        // wave 0..15
    const int lane = tid & 63;
    if (lane < 16) {
#pragma unroll
        for (int c = 0; c < NCLS; ++c)
            red2[(wv_ * 16 + lane) * NCLS + c] = facc[c];
    }
    __syncthreads();

    // ---- combine wave partials -> logits ----
    if (tid < ROWS * NCLS) {          // 320
        int r = tid / NCLS, c = tid - r * NCLS;
        int pp = r >> 1, b = r & 1;
        const float* rf = (const float*)red2;
        float s = fcb[c];
#pragma unroll
        for (int k = 0; k < NWAVE; ++k)
            s += rf[((k * 16 + pp) * NCLS + c) * 2 + b];
        logits[tid] = s;
    }
    __syncthreads();

    // ---- softmax (redundant per-(r,c) thread), coalesced store ----
    if (tid < ROWS * NCLS) {
        int r = tid / NCLS;
        const float* lg = logits + r * NCLS;
        float m = lg[0];
#pragma unroll
        for (int c = 1; c < NCLS; ++c) m = fmaxf(m, lg[c]);
        float s = 0.f;
#pragma unroll
        for (int c = 0; c < NCLS; ++c) s += __expf(lg[c] - m);
        out[(size_t)row0 * NCLS + tid] = __expf(logits[tid] - m) / s;
    }
}

extern "C" void kernel_launch(void* const* d_in, const int* in_sizes, int n_in,
                              void* d_out, int out_size, void* d_ws, size_t ws_size,
                              hipStream_t stream) {
    const float* x    = (const float*)d_in[0];
    const int*   idx1 = (const int*)d_in[1];
    const float* w1   = (const float*)d_in[2];
    const float* b1   = (const float*)d_in[3];
    const int*   idx2 = (const int*)d_in[4];
    const float* w2   = (const float*)d_in[5];
    const float* b2   = (const float*)d_in[6];
    const int*   idx3 = (const int*)d_in[7];
    const float* w3   = (const float*)d_in[8];
    const float* b3   = (const float*)d_in[9];
    const float* fcw  = (const float*)d_in[10];
    const float* fcb  = (const float*)d_in[11];
    float* out = (float*)d_out;

    circnn_kernel<<<dim3(NB), dim3(BLOCK), 0, stream>>>(
        x, idx1, w1, b1, idx2, w2, b2, idx3, w3, b3, fcw, fcb, out);
}

// Round 4
// 769.651 us; speedup vs baseline: 3.1148x; 1.8457x over previous
//
#include <hip/hip_runtime.h>

#define D_    784
#define ROWS  16              // batch rows per block
#define NCLS  10
#define BLOCK 512             // 8 waves
#define NWAVE 8
#define HSTR  18              // dwords per n: 8 row-pairs (16 dw) + 2 pad
#define NPG   13              // n's per 8-lane group: n = g + 64*i
#define NB    (65536 / ROWS)  // 4096 blocks

// pair-slot swizzle: row-pair p of feature n lives at slot (p+n)&7
__device__ __forceinline__ int hoff_pair(int n, int p) {
    return n * HSTR + (((p + n) & 7) << 1);
}
__device__ __forceinline__ int hoff(int n, int r) {
    return hoff_pair(n, r >> 1) + (r & 1);
}

// tanh-approx GELU (|err| vs exact erf-GELU ~5e-4)
__device__ __forceinline__ float gelu_f(float x) {
    float x2    = x * x;
    float inner = fmaf(0.044715f * x, x2, x);
    float e     = exp2f(2.3022082f * inner);          // 2*sqrt(2/pi)*log2(e)
    float r     = __builtin_amdgcn_rcpf(e + 1.0f);
    return fmaf(-x, r, x);                            // x*e/(e+1)
}

// In-place sparse layer. Thread (g = tid>>3, p = tid&7) owns row-pair p for
// n = g + 64*i. Gathers are b64 float2 (rows 2p, 2p+1).
template <int K>
__device__ __forceinline__ void layer_fn(float* __restrict__ h,
                                         const int* __restrict__ idx,
                                         const float* __restrict__ w,
                                         const float* __restrict__ bias,
                                         int g, int p) {
    float2 acc[NPG];
#pragma unroll
    for (int i = 0; i < NPG; ++i) {
        int n = g + 64 * i;
        float2 a = make_float2(0.f, 0.f);
        if (n < D_) {
            float bv = bias[n];
            a.x = bv; a.y = bv;
            if constexpr (K == 2) {
                int2   j2 = *(const int2*)(idx + n * 2);
                float2 wv = *(const float2*)(w + n * 2);
                float2 h0 = *(const float2*)(h + hoff_pair(j2.x, p));
                float2 h1 = *(const float2*)(h + hoff_pair(j2.y, p));
                a.x = fmaf(h0.x, wv.x, a.x); a.y = fmaf(h0.y, wv.x, a.y);
                a.x = fmaf(h1.x, wv.y, a.x); a.y = fmaf(h1.y, wv.y, a.y);
            } else if constexpr (K == 4) {
                int4   j4 = *(const int4*)(idx + n * 4);
                float4 wv = *(const float4*)(w + n * 4);
                float2 h0 = *(const float2*)(h + hoff_pair(j4.x, p));
                float2 h1 = *(const float2*)(h + hoff_pair(j4.y, p));
                float2 h2 = *(const float2*)(h + hoff_pair(j4.z, p));
                float2 h3 = *(const float2*)(h + hoff_pair(j4.w, p));
                a.x = fmaf(h0.x, wv.x, a.x); a.y = fmaf(h0.y, wv.x, a.y);
                a.x = fmaf(h1.x, wv.y, a.x); a.y = fmaf(h1.y, wv.y, a.y);
                a.x = fmaf(h2.x, wv.z, a.x); a.y = fmaf(h2.y, wv.z, a.y);
                a.x = fmaf(h3.x, wv.w, a.x); a.y = fmaf(h3.y, wv.w, a.y);
            } else { // K == 8
                int4   ja = *(const int4*)(idx + n * 8);
                int4   jb = *(const int4*)(idx + n * 8 + 4);
                float4 wa = *(const float4*)(w + n * 8);
                float4 wb = *(const float4*)(w + n * 8 + 4);
                float2 h0 = *(const float2*)(h + hoff_pair(ja.x, p));
                float2 h1 = *(const float2*)(h + hoff_pair(ja.y, p));
                float2 h2 = *(const float2*)(h + hoff_pair(ja.z, p));
                float2 h3 = *(const float2*)(h + hoff_pair(ja.w, p));
                a.x = fmaf(h0.x, wa.x, a.x); a.y = fmaf(h0.y, wa.x, a.y);
                a.x = fmaf(h1.x, wa.y, a.x); a.y = fmaf(h1.y, wa.y, a.y);
                a.x = fmaf(h2.x, wa.z, a.x); a.y = fmaf(h2.y, wa.z, a.y);
                a.x = fmaf(h3.x, wa.w, a.x); a.y = fmaf(h3.y, wa.w, a.y);
                float2 h4 = *(const float2*)(h + hoff_pair(jb.x, p));
                float2 h5 = *(const float2*)(h + hoff_pair(jb.y, p));
                float2 h6 = *(const float2*)(h + hoff_pair(jb.z, p));
                float2 h7 = *(const float2*)(h + hoff_pair(jb.w, p));
                a.x = fmaf(h4.x, wb.x, a.x); a.y = fmaf(h4.y, wb.x, a.y);
                a.x = fmaf(h5.x, wb.y, a.x); a.y = fmaf(h5.y, wb.y, a.y);
                a.x = fmaf(h6.x, wb.z, a.x); a.y = fmaf(h6.y, wb.z, a.y);
                a.x = fmaf(h7.x, wb.w, a.x); a.y = fmaf(h7.y, wb.w, a.y);
            }
        }
        acc[i] = a;
    }
    __syncthreads();
#pragma unroll
    for (int i = 0; i < NPG; ++i) {
        int n = g + 64 * i;
        if (n < D_) {
            float2 gv = make_float2(gelu_f(acc[i].x), gelu_f(acc[i].y));
            *(float2*)(h + hoff_pair(n, p)) = gv;
        }
    }
    __syncthreads();
}

__global__ __launch_bounds__(BLOCK)
void circnn_kernel(const float* __restrict__ x,
                   const int* __restrict__ idx1, const float* __restrict__ w1, const float* __restrict__ b1,
                   const int* __restrict__ idx2, const float* __restrict__ w2, const float* __restrict__ b2,
                   const int* __restrict__ idx3, const float* __restrict__ w3, const float* __restrict__ b3,
                   const float* __restrict__ fcw, const float* __restrict__ fcb,
                   float* __restrict__ out) {
    __shared__ __align__(16) float  h[D_ * HSTR];            // 56,448 B
    __shared__ __align__(16) float2 red2[NWAVE * 8 * NCLS];  // 5,120 B
    __shared__ float logits[ROWS * NCLS];                    // 640 B

    const int tid  = threadIdx.x;
    const int g    = tid >> 3;        // group 0..63
    const int p    = tid & 7;         // row-pair 0..7
    const int row0 = blockIdx.x * ROWS;

    // ---- Stage x: float4 global reads, swizzled scalar LDS writes ----
    const float4* xv = (const float4*)(x + (size_t)row0 * D_);
    for (int q = tid; q < (ROWS * D_) / 4; q += BLOCK) {     // 3136 quads
        float4 v = xv[q];
        int r = q / (D_ / 4);                                // /196
        int n = (q - r * (D_ / 4)) * 4;
        h[hoff(n,     r)] = v.x;
        h[hoff(n + 1, r)] = v.y;
        h[hoff(n + 2, r)] = v.z;
        h[hoff(n + 3, r)] = v.w;
    }
    __syncthreads();

    // ---- Three sparse layers, in place ----
    layer_fn<2>(h, idx1, w1, b1, g, p);
    layer_fn<4>(h, idx2, w2, b2, g, p);
    layer_fn<8>(h, idx3, w3, b3, g, p);

    // ---- FC 784->10: thread (p2 = tid&7 row-pair, jj = tid>>3) ----
    const int p2 = tid & 7;
    const int jj = tid >> 3;          // 0..63
    float2 facc[NCLS];
#pragma unroll
    for (int c = 0; c < NCLS; ++c) facc[c] = make_float2(0.f, 0.f);
#pragma unroll
    for (int i = 0; i < NPG; ++i) {
        int n = jj + 64 * i;
        if (n < D_) {
            float2 hv = *(const float2*)(h + hoff_pair(n, p2));
#pragma unroll
            for (int c = 0; c < NCLS; ++c) {
                float wv = fcw[c * D_ + n];
                facc[c].x = fmaf(hv.x, wv, facc[c].x);
                facc[c].y = fmaf(hv.y, wv, facc[c].y);
            }
        }
    }
    // reduce over jj-within-wave (tid bits 3,4,5)
#pragma unroll
    for (int m = 8; m <= 32; m <<= 1) {
#pragma unroll
        for (int c = 0; c < NCLS; ++c) {
            facc[c].x += __shfl_xor(facc[c].x, m, 64);
            facc[c].y += __shfl_xor(facc[c].y, m, 64);
        }
    }
    const int wv_  = tid >> 6;        // wave 0..7
    const int lane = tid & 63;
    if (lane < 8) {
#pragma unroll
        for (int c = 0; c < NCLS; ++c)
            red2[(wv_ * 8 + lane) * NCLS + c] = facc[c];
    }
    __syncthreads();

    // ---- combine wave partials -> logits[r][c] ----
    if (tid < ROWS * NCLS) {          // 160 threads
        int r = tid / NCLS, c = tid - r * NCLS;
        int pp = r >> 1, b = r & 1;
        const float* rf = (const float*)red2;
        float s = fcb[c];
#pragma unroll
        for (int k = 0; k < NWAVE; ++k)
            s += rf[((k * 8 + pp) * NCLS + c) * 2 + b];
        logits[tid] = s;
    }
    __syncthreads();

    // ---- softmax (redundant per-(r,c) thread), coalesced 160-float store ----
    if (tid < ROWS * NCLS) {
        int r = tid / NCLS;
        const float* lg = logits + r * NCLS;
        float m = lg[0];
#pragma unroll
        for (int c = 1; c < NCLS; ++c) m = fmaxf(m, lg[c]);
        float s = 0.f;
#pragma unroll
        for (int c = 0; c < NCLS; ++c) s += __expf(lg[c] - m);
        out[(size_t)row0 * NCLS + tid] = __expf(logits[tid] - m) / s;
    }
}

extern "C" void kernel_launch(void* const* d_in, const int* in_sizes, int n_in,
                              void* d_out, int out_size, void* d_ws, size_t ws_size,
                              hipStream_t stream) {
    const float* x    = (const float*)d_in[0];
    const int*   idx1 = (const int*)d_in[1];
    const float* w1   = (const float*)d_in[2];
    const float* b1   = (const float*)d_in[3];
    const int*   idx2 = (const int*)d_in[4];
    const float* w2   = (const float*)d_in[5];
    const float* b2   = (const float*)d_in[6];
    const int*   idx3 = (const int*)d_in[7];
    const float* w3   = (const float*)d_in[8];
    const float* b3   = (const float*)d_in[9];
    const float* fcw  = (const float*)d_in[10];
    const float* fcb  = (const float*)d_in[11];
    float* out = (float*)d_out;

    circnn_kernel<<<dim3(NB), dim3(BLOCK), 0, stream>>>(
        x, idx1, w1, b1, idx2, w2, b2, idx3, w3, b3, fcw, fcb, out);
}